// Round 6
// baseline (338.934 us; speedup 1.0000x reference)
//
#include <hip/hip_runtime.h>
#include <cstdint>
#include <cstddef>

// EinsteinPINN — analytic forward-mode rewrite, MFMA pass-2, barrier-free waves.
// Round 5: occupancy push. Half-K staging (Gt halved to [16][136], two
// stage->mfma phases reusing the buffer), U_s eliminated via quad-shuffle,
// LDS 49152->31744 B (3->5 blocks/CU), ITERS 8->4 (grid 4096).
// Math (verified rounds 1-4): e = I + 0.1*(W2 h + b2); de[m]=0.1*W2(g.*W1[:,m]);
//   dde[p,q]=0.1*W2(u.*W1[:,p].*W1[:,q]); h=tanh(z), g=1-h^2, u=-2hg.
//   A=inv(e); F = de - de^T(first two); Ad_d = -A de_d A;
//   riemann[m,n,i,j] = (eta_i/2) sum_a [Ad_m[i,a]F[n,a,j] - Ad_n[i,a]F[m,a,j]
//                                       + A[i,a](dde[n,a,m,j]-dde[m,a,n,j])]
//   (antisym in (m,n): 6 pairs). Outputs are cheap A-contractions of R.

typedef _Float16 h2   __attribute__((ext_vector_type(2)));
typedef _Float16 f16x8 __attribute__((ext_vector_type(8)));
typedef float    f32x4 __attribute__((ext_vector_type(4)));

#define WAVES 4
#define ITERS 4

__device__ __forceinline__ void wfence() {
  // order all prior LDS ops before subsequent ones, wave-locally (no s_barrier)
  asm volatile("s_waitcnt lgkmcnt(0)" ::: "memory");
  __builtin_amdgcn_sched_barrier(0);
}

__device__ __forceinline__ unsigned pkrtz(float a, float b) {
#if __has_builtin(__builtin_amdgcn_cvt_pkrtz)
  return __builtin_bit_cast(unsigned, __builtin_amdgcn_cvt_pkrtz(a, b));
#else
  h2 v; v[0] = (_Float16)a; v[1] = (_Float16)b;
  return __builtin_bit_cast(unsigned, v);
#endif
}

__global__ __launch_bounds__(256, 5) void ein_kernel(
    const float* __restrict__ x, const float* __restrict__ W1,
    const float* __restrict__ b1, const float* __restrict__ W2,
    const float* __restrict__ b2, float* __restrict__ out, int B)
{
  // ---- per-wave LDS (31744 B total -> 5 blocks/CU, 20 waves) ----
  __shared__ __align__(16) _Float16 Gt[WAVES][16][136]; // half-K G^T: [c][n0..127]+8 pad
  __shared__ __align__(16) float Qs[WAVES][320];        // M cols, stride 20: c*20 + r
  __shared__ __align__(16) float dde2[WAVES][320];      // [p*4+q][r], stride 20, sym-dup
  __shared__ __align__(16) float A_s[WAVES][16];
  __shared__ float F_s[WAVES][64];
  __shared__ float Ad_s[WAVES][64];
  __shared__ __align__(16) float R_s[WAVES][96];        // 6 pairs x 16
  __shared__ float rp_s[WAVES][16];

  const int tid  = threadIdx.x;
  const int wv   = tid >> 6;
  const int lane = tid & 63;
  const int l15  = lane & 15;
  const int hb   = lane >> 4;
  const int dd = lane >> 4, ii = (lane >> 2) & 3, jj = lane & 3;
  const float eta_ii = (ii == 0) ? -1.f : 1.f;

  // ---- loop-invariant register state ----
  // W1 rows + b1 for this lane's 4 neurons: 2*lane, 2*lane+1, 2*lane+128, 2*lane+129
  const float4 w1A = ((const float4*)W1)[2*lane];
  const float4 w1B = ((const float4*)W1)[2*lane + 1];
  const float4 w1C = ((const float4*)W1)[2*lane + 128];
  const float4 w1D = ((const float4*)W1)[2*lane + 129];
  const float b1A = b1[2*lane],       b1B = b1[2*lane + 1];
  const float b1C = b1[2*lane + 128], b1D = b1[2*lane + 129];
  // MFMA A-fragments: lane holds W2[row=l15][k = cc*32 + hb*8 + j], j=0..7
  f16x8 afr[8];
  #pragma unroll
  for (int cc = 0; cc < 8; ++cc) {
    const float* p = W2 + l15*256 + cc*32 + hb*8;
    float4 u0 = ((const float4*)p)[0];
    float4 u1 = ((const float4*)p)[1];
    f16x8 a;
    a[0]=(_Float16)u0.x; a[1]=(_Float16)u0.y; a[2]=(_Float16)u0.z; a[3]=(_Float16)u0.w;
    a[4]=(_Float16)u1.x; a[5]=(_Float16)u1.y; a[6]=(_Float16)u1.z; a[7]=(_Float16)u1.w;
    afr[cc] = a;
  }
  const float eb0 = b2[4*hb+0], eb1 = b2[4*hb+1], eb2 = b2[4*hb+2], eb3 = b2[4*hb+3];

  float* out0 = out;
  float* out1 = out + (size_t)B * 16;

  // per-neuron activation pieces: h, g*w (4), u*w (4)
  auto neuron = [](const float4& w, float b, const float4& xs,
                   float& h, float4& gw4, float4& uw4) {
    float z = b + w.x*xs.x + w.y*xs.y + w.z*xs.z + w.w*xs.w;
    float t  = __expf(-2.f * fabsf(z));
    float r1 = __builtin_amdgcn_rcpf(1.f + t);
    float habs = (1.f - t) * r1;
    h = (z < 0.f) ? -habs : habs;
    float g = 4.f * t * r1 * r1;         // sech^2, no cancellation
    float u = -2.f * h * g;
    gw4 = make_float4(g*w.x, g*w.y, g*w.z, g*w.w);
    uw4 = make_float4(u*w.x, u*w.y, u*w.z, u*w.w);
  };

  const int sbase = blockIdx.x * (WAVES * ITERS);
  float4 xs = ((const float4*)x)[sbase + wv];

  for (int it = 0; it < ITERS; ++it) {
    const int s = sbase + it * WAVES + wv;
    const float4 xc = xs;
    if (it + 1 < ITERS) xs = ((const float4*)x)[sbase + (it + 1) * WAVES + wv];

    // ---------- pass 1+2 interleaved: two half-K phases over one Gt buffer ----
    // stage: lane stages neuron pair (f16 packed); writes u32 word c*68 + lane
    unsigned* gwp = (unsigned*)&Gt[wv][0][0] + lane;   // row stride 68 u32
    auto stage_pair = [&](const float4& wA, float bA_, const float4& wB, float bB_) {
      float hA, hB; float4 gA, gB, uA, uB;
      neuron(wA, bA_, xc, hA, gA, uA);
      neuron(wB, bB_, xc, hB, gB, uB);
      gwp[0*68] = pkrtz(hA, hB);
      gwp[1*68] = pkrtz(gA.x, gB.x);  gwp[2*68] = pkrtz(gA.y, gB.y);
      gwp[3*68] = pkrtz(gA.z, gB.z);  gwp[4*68] = pkrtz(gA.w, gB.w);
      gwp[5*68]  = pkrtz(uA.x*wA.x, uB.x*wB.x);
      gwp[6*68]  = pkrtz(uA.x*wA.y, uB.x*wB.y);
      gwp[7*68]  = pkrtz(uA.x*wA.z, uB.x*wB.z);
      gwp[8*68]  = pkrtz(uA.x*wA.w, uB.x*wB.w);
      gwp[9*68]  = pkrtz(uA.y*wA.y, uB.y*wB.y);
      gwp[10*68] = pkrtz(uA.y*wA.z, uB.y*wB.z);
      gwp[11*68] = pkrtz(uA.y*wA.w, uB.y*wB.w);
      gwp[12*68] = pkrtz(uA.z*wA.z, uB.z*wB.z);
      gwp[13*68] = pkrtz(uA.z*wA.w, uB.z*wB.w);
      gwp[14*68] = pkrtz(uA.w*wA.w, uB.w*wB.w);
    };
    // B-frag reads: lane (l15,hb) reads Gt[l15][kk*32 + hb*8 ..+7] (16B aligned)
    const f16x8* gp = (const f16x8*)&Gt[wv][l15][hb*8];

    f32x4 acc = {0.f, 0.f, 0.f, 0.f};
    stage_pair(w1A, b1A, w1B, b1B);          // neurons 0..127
    wfence();
    #pragma unroll
    for (int kk = 0; kk < 4; ++kk) {
      f16x8 bfr = gp[kk * 4];
      acc = __builtin_amdgcn_mfma_f32_16x16x32_f16(afr[kk], bfr, acc, 0, 0, 0);
    }
    wfence();                                 // reads drained before overwrite
    stage_pair(w1C, b1C, w1D, b1D);          // neurons 128..255
    wfence();
    #pragma unroll
    for (int kk = 0; kk < 4; ++kk) {
      f16x8 bfr = gp[kk * 4];
      acc = __builtin_amdgcn_mfma_f32_16x16x32_f16(afr[4 + kk], bfr, acc, 0, 0, 0);
    }

    // ---------- writeback: lane holds M[r=4*hb+q][c=l15] in acc[q] ----------
    {
      float v0 = 0.1f*acc[0], v1 = 0.1f*acc[1], v2 = 0.1f*acc[2], v3 = 0.1f*acc[3];
      if (l15 == 0) {   // e column: + 0.1*b2 + I   (r=4hb+q -> i=hb, j=q)
        v0 += 0.1f*eb0 + ((hb == 0) ? 1.f : 0.f);
        v1 += 0.1f*eb1 + ((hb == 1) ? 1.f : 0.f);
        v2 += 0.1f*eb2 + ((hb == 2) ? 1.f : 0.f);
        v3 += 0.1f*eb3 + ((hb == 3) ? 1.f : 0.f);
      }
      float4 v4 = make_float4(v0, v1, v2, v3);
      *(float4*)&Qs[wv][l15*20 + hb*4] = v4;
      if (l15 >= 5 && l15 <= 14) {       // dde columns -> [p][q] grid with sym dup
        int t = l15 - 5;                  // 0..9, pairs (0,0),(0,1),(0,2),(0,3),(1,1),...
        int p = (t >= 9) ? 3 : (t >= 7) ? 2 : (t >= 4) ? 1 : 0;
        int q = t - ((p * (7 - p)) >> 1);
        *(float4*)&dde2[wv][(p*4 + q)*20 + hb*4] = v4;
        if (p != q) *(float4*)&dde2[wv][(q*4 + p)*20 + hb*4] = v4;
      }
    }
    wfence();

    // ---------- phase 3 ----------
    // (a) A = inv(e), all lanes redundant (cofactor)
    {
      float4 er0 = *(const float4*)&Qs[wv][0];
      float4 er1 = *(const float4*)&Qs[wv][4];
      float4 er2 = *(const float4*)&Qs[wv][8];
      float4 er3 = *(const float4*)&Qs[wv][12];
      float m00=er0.x,m01=er0.y,m02=er0.z,m03=er0.w;
      float m10=er1.x,m11=er1.y,m12=er1.z,m13=er1.w;
      float m20=er2.x,m21=er2.y,m22=er2.z,m23=er2.w;
      float m30=er3.x,m31=er3.y,m32=er3.z,m33=er3.w;
      float s0_=m00*m11-m01*m10, s1_=m00*m12-m02*m10, s2_=m00*m13-m03*m10;
      float s3_=m01*m12-m02*m11, s4_=m01*m13-m03*m11, s5_=m02*m13-m03*m12;
      float c5_=m22*m33-m23*m32, c4_=m21*m33-m23*m31, c3_=m21*m32-m22*m31;
      float c2_=m20*m33-m23*m30, c1_=m20*m32-m22*m30, c0_=m20*m31-m21*m30;
      float det = s0_*c5_ - s1_*c4_ + s2_*c3_ + s3_*c2_ - s4_*c1_ + s5_*c0_;
      float inv = 1.0f / det;
      if (lane == 0) {
        *(float4*)&A_s[wv][0]  = make_float4(( m11*c5_-m12*c4_+m13*c3_)*inv,
                                             (-m01*c5_+m02*c4_-m03*c3_)*inv,
                                             ( m31*s5_-m32*s4_+m33*s3_)*inv,
                                             (-m21*s5_+m22*s4_-m23*s3_)*inv);
        *(float4*)&A_s[wv][4]  = make_float4((-m10*c5_+m12*c2_-m13*c1_)*inv,
                                             ( m00*c5_-m02*c2_+m03*c1_)*inv,
                                             (-m30*s5_+m32*s2_-m33*s1_)*inv,
                                             ( m20*s5_-m22*s2_+m23*s1_)*inv);
        *(float4*)&A_s[wv][8]  = make_float4(( m10*c4_-m11*c2_+m13*c0_)*inv,
                                             (-m00*c4_+m01*c2_-m03*c0_)*inv,
                                             ( m30*s4_-m31*s2_+m33*s0_)*inv,
                                             (-m20*s4_+m21*s2_-m23*s0_)*inv);
        *(float4*)&A_s[wv][12] = make_float4((-m10*c3_+m11*c1_-m12*c0_)*inv,
                                             ( m00*c3_-m01*c1_+m02*c0_)*inv,
                                             (-m30*s3_+m31*s1_-m32*s0_)*inv,
                                             ( m20*s3_-m21*s1_+m22*s0_)*inv);
      }
    }
    wfence();

    // (b) F = de - de^T(first two); (c) u = A[ii,:].de[dd,:,jj];
    // (d) Ad_d = -U_d A via quad-shuffle (U row lives in this 4-lane group)
    F_s[wv][dd*16 + ii*4 + jj] = Qs[wv][(1+dd)*20 + ii*4 + jj]
                               - Qs[wv][(1+ii)*20 + dd*4 + jj];
    {
      float4 Ai = *(const float4*)&A_s[wv][ii*4];
      float u =
          Ai.x * Qs[wv][(1+dd)*20 +  0 + jj] + Ai.y * Qs[wv][(1+dd)*20 +  4 + jj]
        + Ai.z * Qs[wv][(1+dd)*20 +  8 + jj] + Ai.w * Qs[wv][(1+dd)*20 + 12 + jj];
      float Adv = -( __shfl(u, 0, 4) * A_s[wv][ 0 + jj]
                   + __shfl(u, 1, 4) * A_s[wv][ 4 + jj]
                   + __shfl(u, 2, 4) * A_s[wv][ 8 + jj]
                   + __shfl(u, 3, 4) * A_s[wv][12 + jj] );
      Ad_s[wv][dd*16 + ii*4 + jj] = Adv;
    }
    wfence();

    // (e) R[(m,n)][i][j], 6 antisym pairs   [dde[p][q][r] = dde2[(p*4+q)*20+r]]
    {
      auto riem = [&](int m, int n) -> float {
        float4 Adm = *(const float4*)&Ad_s[wv][m*16 + ii*4];
        float4 Adn = *(const float4*)&Ad_s[wv][n*16 + ii*4];
        float4 Aiv = *(const float4*)&A_s[wv][ii*4];
        float a;
        a  = Adm.x * F_s[wv][n*16 +  0 + jj] - Adn.x * F_s[wv][m*16 +  0 + jj]
           + Aiv.x * (dde2[wv][(n*4+0)*20 + m*4 + jj] - dde2[wv][(m*4+0)*20 + n*4 + jj]);
        a += Adm.y * F_s[wv][n*16 +  4 + jj] - Adn.y * F_s[wv][m*16 +  4 + jj]
           + Aiv.y * (dde2[wv][(n*4+1)*20 + m*4 + jj] - dde2[wv][(m*4+1)*20 + n*4 + jj]);
        a += Adm.z * F_s[wv][n*16 +  8 + jj] - Adn.z * F_s[wv][m*16 +  8 + jj]
           + Aiv.z * (dde2[wv][(n*4+2)*20 + m*4 + jj] - dde2[wv][(m*4+2)*20 + n*4 + jj]);
        a += Adm.w * F_s[wv][n*16 + 12 + jj] - Adn.w * F_s[wv][m*16 + 12 + jj]
           + Aiv.w * (dde2[wv][(n*4+3)*20 + m*4 + jj] - dde2[wv][(m*4+3)*20 + n*4 + jj]);
        return 0.5f * eta_ii * a;
      };
      int m1 = (dd < 3) ? 0 : 1;
      int n1 = (dd < 3) ? (dd + 1) : 2;          // pairs 0..3: (0,1),(0,2),(0,3),(1,2)
      R_s[wv][dd*16 + ii*4 + jj] = riem(m1, n1);
      if (dd < 2)                                 // pairs 4,5: (1,3),(2,3)
        R_s[wv][(4 + dd)*16 + ii*4 + jj] = riem(dd + 1, 3);
    }
    wfence();

    // (f) riemann_out[k,l,i,j] = eta_k eta_l sum_p minor_p(A;k,l) R_p[i,j]
    {
      const int kl = lane >> 2, kk = kl >> 2, ll = kl & 3, i2 = lane & 3;
      float4 akv = *(const float4*)&A_s[wv][kk*4];
      float4 alv = *(const float4*)&A_s[wv][ll*4];
      float sgn = ((kk == 0) != (ll == 0)) ? -1.f : 1.f;
      float B0 = (akv.x*alv.y - akv.y*alv.x) * sgn;
      float B1 = (akv.x*alv.z - akv.z*alv.x) * sgn;
      float B2 = (akv.x*alv.w - akv.w*alv.x) * sgn;
      float B3 = (akv.y*alv.z - akv.z*alv.y) * sgn;
      float B4 = (akv.y*alv.w - akv.w*alv.y) * sgn;
      float B5 = (akv.z*alv.w - akv.w*alv.z) * sgn;
      float4 r0 = *(const float4*)&R_s[wv][ 0 + i2*4];
      float4 r1 = *(const float4*)&R_s[wv][16 + i2*4];
      float4 r2 = *(const float4*)&R_s[wv][32 + i2*4];
      float4 r3 = *(const float4*)&R_s[wv][48 + i2*4];
      float4 r4 = *(const float4*)&R_s[wv][64 + i2*4];
      float4 r5 = *(const float4*)&R_s[wv][80 + i2*4];
      float4 o;
      o.x = B0*r0.x + B1*r1.x + B2*r2.x + B3*r3.x + B4*r4.x + B5*r5.x;
      o.y = B0*r0.y + B1*r1.y + B2*r2.y + B3*r3.y + B4*r4.y + B5*r5.y;
      o.z = B0*r0.z + B1*r1.z + B2*r2.z + B3*r3.z + B4*r4.z + B5*r5.z;
      o.w = B0*r0.w + B1*r1.w + B2*r2.w + B3*r3.w + B4*r4.w + B5*r5.w;
      ((float4*)(out1 + ((size_t)s << 8)))[kl*4 + i2] = o;
    }
    // (g1) rp[m,j'] = sum over n of sgn * R[(m,n)] col-contraction with A
    if (ii == 0) {
      const int m = dd, ip = jj;
      float a = 0.f;
      #pragma unroll
      for (int n = 0; n < 4; ++n) {
        if (n != m) {
          int mm = (m < n) ? m : n;
          int nn = (m < n) ? n : m;
          int pr = mm * (7 - mm) / 2 + (nn - mm - 1);
          float sg = (m < n) ? 1.f : -1.f;
          float4 rr = *(const float4*)&R_s[wv][pr*16 + ip*4];
          a += sg * (rr.x * A_s[wv][0 + n] + rr.y * A_s[wv][4 + n]
                   + rr.z * A_s[wv][8 + n] + rr.w * A_s[wv][12 + n]);
        }
      }
      rp_s[wv][m*4 + ip] = a;
    }
    wfence();
    // (g2) ricci[i,j] = eta_i sum_m A[i,m] rp[m,j]
    if (dd == 0) {
      float4 Ai = *(const float4*)&A_s[wv][ii*4];
      float a = Ai.x * rp_s[wv][0 + jj] + Ai.y * rp_s[wv][4 + jj]
              + Ai.z * rp_s[wv][8 + jj] + Ai.w * rp_s[wv][12 + jj];
      out0[(size_t)s * 16 + ii*4 + jj] = eta_ii * a;
    }
  }
}

extern "C" void kernel_launch(void* const* d_in, const int* in_sizes, int n_in,
                              void* d_out, int out_size, void* d_ws, size_t ws_size,
                              hipStream_t stream) {
  (void)n_in; (void)out_size; (void)d_ws; (void)ws_size;
  const float* x  = (const float*)d_in[0];
  const float* W1 = (const float*)d_in[1];
  const float* b1 = (const float*)d_in[2];
  const float* W2 = (const float*)d_in[3];
  const float* b2 = (const float*)d_in[4];
  float* out = (float*)d_out;
  const int B = in_sizes[0] / 4;                 // 65536
  const int nblk = B / (WAVES * ITERS);          // 4096 blocks x 256 threads
  hipLaunchKernelGGL(ein_kernel, dim3(nblk), dim3(256), 0, stream,
                     x, W1, b1, W2, b2, out, B);
}

// Round 10
// 258.731 us; speedup vs baseline: 1.3100x; 1.3100x over previous
//
#include <hip/hip_runtime.h>
#include <cstdint>
#include <cstddef>

// EinsteinPINN — analytic forward-mode rewrite, MFMA pass-2, barrier-free waves.
// Round 7: fix round-6 spill disaster. launch_bounds(256,5) forced VGPR<=64
// (occupancy quantum is 64/128/256 per learn_hip m69), spilling ~20 regs ->
// 545 MB scratch FETCH. Revert to (256,4): VGPR cap 128, natural ~84, no
// spill; occupancy = min(LDS 5 blk, VGPR 4 waves/SIMD) = 4 blk/CU (50%).
// Math (verified rounds 1-6): e = I + 0.1*(W2 h + b2); de[m]=0.1*W2(g.*W1[:,m]);
//   dde[p,q]=0.1*W2(u.*W1[:,p].*W1[:,q]); h=tanh(z), g=1-h^2, u=-2hg.
//   A=inv(e); F = de - de^T(first two); Ad_d = -A de_d A;
//   riemann[m,n,i,j] = (eta_i/2) sum_a [Ad_m[i,a]F[n,a,j] - Ad_n[i,a]F[m,a,j]
//                                       + A[i,a](dde[n,a,m,j]-dde[m,a,n,j])]
//   (antisym in (m,n): 6 pairs). Outputs are cheap A-contractions of R.

typedef _Float16 h2   __attribute__((ext_vector_type(2)));
typedef _Float16 f16x8 __attribute__((ext_vector_type(8)));
typedef float    f32x4 __attribute__((ext_vector_type(4)));

#define WAVES 4
#define ITERS 4

__device__ __forceinline__ void wfence() {
  // order all prior LDS ops before subsequent ones, wave-locally (no s_barrier)
  asm volatile("s_waitcnt lgkmcnt(0)" ::: "memory");
  __builtin_amdgcn_sched_barrier(0);
}

__device__ __forceinline__ unsigned pkrtz(float a, float b) {
#if __has_builtin(__builtin_amdgcn_cvt_pkrtz)
  return __builtin_bit_cast(unsigned, __builtin_amdgcn_cvt_pkrtz(a, b));
#else
  h2 v; v[0] = (_Float16)a; v[1] = (_Float16)b;
  return __builtin_bit_cast(unsigned, v);
#endif
}

__global__ __launch_bounds__(256, 4) void ein_kernel(
    const float* __restrict__ x, const float* __restrict__ W1,
    const float* __restrict__ b1, const float* __restrict__ W2,
    const float* __restrict__ b2, float* __restrict__ out, int B)
{
  // ---- per-wave LDS (31744 B total; LDS allows 5 blk/CU, VGPR gives 4) ----
  __shared__ __align__(16) _Float16 Gt[WAVES][16][136]; // half-K G^T: [c][n0..127]+8 pad
  __shared__ __align__(16) float Qs[WAVES][320];        // M cols, stride 20: c*20 + r
  __shared__ __align__(16) float dde2[WAVES][320];      // [p*4+q][r], stride 20, sym-dup
  __shared__ __align__(16) float A_s[WAVES][16];
  __shared__ float F_s[WAVES][64];
  __shared__ float Ad_s[WAVES][64];
  __shared__ __align__(16) float R_s[WAVES][96];        // 6 pairs x 16
  __shared__ float rp_s[WAVES][16];

  const int tid  = threadIdx.x;
  const int wv   = tid >> 6;
  const int lane = tid & 63;
  const int l15  = lane & 15;
  const int hb   = lane >> 4;
  const int dd = lane >> 4, ii = (lane >> 2) & 3, jj = lane & 3;
  const float eta_ii = (ii == 0) ? -1.f : 1.f;

  // ---- loop-invariant register state ----
  // W1 rows + b1 for this lane's 4 neurons: 2*lane, 2*lane+1, 2*lane+128, 2*lane+129
  const float4 w1A = ((const float4*)W1)[2*lane];
  const float4 w1B = ((const float4*)W1)[2*lane + 1];
  const float4 w1C = ((const float4*)W1)[2*lane + 128];
  const float4 w1D = ((const float4*)W1)[2*lane + 129];
  const float b1A = b1[2*lane],       b1B = b1[2*lane + 1];
  const float b1C = b1[2*lane + 128], b1D = b1[2*lane + 129];
  // MFMA A-fragments: lane holds W2[row=l15][k = cc*32 + hb*8 + j], j=0..7
  f16x8 afr[8];
  #pragma unroll
  for (int cc = 0; cc < 8; ++cc) {
    const float* p = W2 + l15*256 + cc*32 + hb*8;
    float4 u0 = ((const float4*)p)[0];
    float4 u1 = ((const float4*)p)[1];
    f16x8 a;
    a[0]=(_Float16)u0.x; a[1]=(_Float16)u0.y; a[2]=(_Float16)u0.z; a[3]=(_Float16)u0.w;
    a[4]=(_Float16)u1.x; a[5]=(_Float16)u1.y; a[6]=(_Float16)u1.z; a[7]=(_Float16)u1.w;
    afr[cc] = a;
  }
  const float eb0 = b2[4*hb+0], eb1 = b2[4*hb+1], eb2 = b2[4*hb+2], eb3 = b2[4*hb+3];

  float* out0 = out;
  float* out1 = out + (size_t)B * 16;

  // per-neuron activation pieces: h, g*w (4), u*w (4)
  auto neuron = [](const float4& w, float b, const float4& xs,
                   float& h, float4& gw4, float4& uw4) {
    float z = b + w.x*xs.x + w.y*xs.y + w.z*xs.z + w.w*xs.w;
    float t  = __expf(-2.f * fabsf(z));
    float r1 = __builtin_amdgcn_rcpf(1.f + t);
    float habs = (1.f - t) * r1;
    h = (z < 0.f) ? -habs : habs;
    float g = 4.f * t * r1 * r1;         // sech^2, no cancellation
    float u = -2.f * h * g;
    gw4 = make_float4(g*w.x, g*w.y, g*w.z, g*w.w);
    uw4 = make_float4(u*w.x, u*w.y, u*w.z, u*w.w);
  };

  const int sbase = blockIdx.x * (WAVES * ITERS);
  float4 xs = ((const float4*)x)[sbase + wv];

  for (int it = 0; it < ITERS; ++it) {
    const int s = sbase + it * WAVES + wv;
    const float4 xc = xs;
    if (it + 1 < ITERS) xs = ((const float4*)x)[sbase + (it + 1) * WAVES + wv];

    // ---------- pass 1+2 interleaved: two half-K phases over one Gt buffer ----
    // stage: lane stages neuron pair (f16 packed); writes u32 word c*68 + lane
    unsigned* gwp = (unsigned*)&Gt[wv][0][0] + lane;   // row stride 68 u32
    auto stage_pair = [&](const float4& wA, float bA_, const float4& wB, float bB_) {
      float hA, hB; float4 gA, gB, uA, uB;
      neuron(wA, bA_, xc, hA, gA, uA);
      neuron(wB, bB_, xc, hB, gB, uB);
      gwp[0*68] = pkrtz(hA, hB);
      gwp[1*68] = pkrtz(gA.x, gB.x);  gwp[2*68] = pkrtz(gA.y, gB.y);
      gwp[3*68] = pkrtz(gA.z, gB.z);  gwp[4*68] = pkrtz(gA.w, gB.w);
      gwp[5*68]  = pkrtz(uA.x*wA.x, uB.x*wB.x);
      gwp[6*68]  = pkrtz(uA.x*wA.y, uB.x*wB.y);
      gwp[7*68]  = pkrtz(uA.x*wA.z, uB.x*wB.z);
      gwp[8*68]  = pkrtz(uA.x*wA.w, uB.x*wB.w);
      gwp[9*68]  = pkrtz(uA.y*wA.y, uB.y*wB.y);
      gwp[10*68] = pkrtz(uA.y*wA.z, uB.y*wB.z);
      gwp[11*68] = pkrtz(uA.y*wA.w, uB.y*wB.w);
      gwp[12*68] = pkrtz(uA.z*wA.z, uB.z*wB.z);
      gwp[13*68] = pkrtz(uA.z*wA.w, uB.z*wB.w);
      gwp[14*68] = pkrtz(uA.w*wA.w, uB.w*wB.w);
    };
    // B-frag reads: lane (l15,hb) reads Gt[l15][kk*32 + hb*8 ..+7] (16B aligned)
    const f16x8* gp = (const f16x8*)&Gt[wv][l15][hb*8];

    f32x4 acc = {0.f, 0.f, 0.f, 0.f};
    stage_pair(w1A, b1A, w1B, b1B);          // neurons 0..127
    wfence();
    #pragma unroll
    for (int kk = 0; kk < 4; ++kk) {
      f16x8 bfr = gp[kk * 4];
      acc = __builtin_amdgcn_mfma_f32_16x16x32_f16(afr[kk], bfr, acc, 0, 0, 0);
    }
    wfence();                                 // reads drained before overwrite
    stage_pair(w1C, b1C, w1D, b1D);          // neurons 128..255
    wfence();
    #pragma unroll
    for (int kk = 0; kk < 4; ++kk) {
      f16x8 bfr = gp[kk * 4];
      acc = __builtin_amdgcn_mfma_f32_16x16x32_f16(afr[4 + kk], bfr, acc, 0, 0, 0);
    }

    // ---------- writeback: lane holds M[r=4*hb+q][c=l15] in acc[q] ----------
    {
      float v0 = 0.1f*acc[0], v1 = 0.1f*acc[1], v2 = 0.1f*acc[2], v3 = 0.1f*acc[3];
      if (l15 == 0) {   // e column: + 0.1*b2 + I   (r=4hb+q -> i=hb, j=q)
        v0 += 0.1f*eb0 + ((hb == 0) ? 1.f : 0.f);
        v1 += 0.1f*eb1 + ((hb == 1) ? 1.f : 0.f);
        v2 += 0.1f*eb2 + ((hb == 2) ? 1.f : 0.f);
        v3 += 0.1f*eb3 + ((hb == 3) ? 1.f : 0.f);
      }
      float4 v4 = make_float4(v0, v1, v2, v3);
      *(float4*)&Qs[wv][l15*20 + hb*4] = v4;
      if (l15 >= 5 && l15 <= 14) {       // dde columns -> [p][q] grid with sym dup
        int t = l15 - 5;                  // 0..9, pairs (0,0),(0,1),(0,2),(0,3),(1,1),...
        int p = (t >= 9) ? 3 : (t >= 7) ? 2 : (t >= 4) ? 1 : 0;
        int q = t - ((p * (7 - p)) >> 1);
        *(float4*)&dde2[wv][(p*4 + q)*20 + hb*4] = v4;
        if (p != q) *(float4*)&dde2[wv][(q*4 + p)*20 + hb*4] = v4;
      }
    }
    wfence();

    // ---------- phase 3 ----------
    // (a) A = inv(e), all lanes redundant (cofactor)
    {
      float4 er0 = *(const float4*)&Qs[wv][0];
      float4 er1 = *(const float4*)&Qs[wv][4];
      float4 er2 = *(const float4*)&Qs[wv][8];
      float4 er3 = *(const float4*)&Qs[wv][12];
      float m00=er0.x,m01=er0.y,m02=er0.z,m03=er0.w;
      float m10=er1.x,m11=er1.y,m12=er1.z,m13=er1.w;
      float m20=er2.x,m21=er2.y,m22=er2.z,m23=er2.w;
      float m30=er3.x,m31=er3.y,m32=er3.z,m33=er3.w;
      float s0_=m00*m11-m01*m10, s1_=m00*m12-m02*m10, s2_=m00*m13-m03*m10;
      float s3_=m01*m12-m02*m11, s4_=m01*m13-m03*m11, s5_=m02*m13-m03*m12;
      float c5_=m22*m33-m23*m32, c4_=m21*m33-m23*m31, c3_=m21*m32-m22*m31;
      float c2_=m20*m33-m23*m30, c1_=m20*m32-m22*m30, c0_=m20*m31-m21*m30;
      float det = s0_*c5_ - s1_*c4_ + s2_*c3_ + s3_*c2_ - s4_*c1_ + s5_*c0_;
      float inv = 1.0f / det;
      if (lane == 0) {
        *(float4*)&A_s[wv][0]  = make_float4(( m11*c5_-m12*c4_+m13*c3_)*inv,
                                             (-m01*c5_+m02*c4_-m03*c3_)*inv,
                                             ( m31*s5_-m32*s4_+m33*s3_)*inv,
                                             (-m21*s5_+m22*s4_-m23*s3_)*inv);
        *(float4*)&A_s[wv][4]  = make_float4((-m10*c5_+m12*c2_-m13*c1_)*inv,
                                             ( m00*c5_-m02*c2_+m03*c1_)*inv,
                                             (-m30*s5_+m32*s2_-m33*s1_)*inv,
                                             ( m20*s5_-m22*s2_+m23*s1_)*inv);
        *(float4*)&A_s[wv][8]  = make_float4(( m10*c4_-m11*c2_+m13*c0_)*inv,
                                             (-m00*c4_+m01*c2_-m03*c0_)*inv,
                                             ( m30*s4_-m31*s2_+m33*s0_)*inv,
                                             (-m20*s4_+m21*s2_-m23*s0_)*inv);
        *(float4*)&A_s[wv][12] = make_float4((-m10*c3_+m11*c1_-m12*c0_)*inv,
                                             ( m00*c3_-m01*c1_+m02*c0_)*inv,
                                             (-m30*s3_+m31*s1_-m32*s0_)*inv,
                                             ( m20*s3_-m21*s1_+m22*s0_)*inv);
      }
    }
    wfence();

    // (b) F = de - de^T(first two); (c) u = A[ii,:].de[dd,:,jj];
    // (d) Ad_d = -U_d A via quad-shuffle (U row lives in this 4-lane group)
    F_s[wv][dd*16 + ii*4 + jj] = Qs[wv][(1+dd)*20 + ii*4 + jj]
                               - Qs[wv][(1+ii)*20 + dd*4 + jj];
    {
      float4 Ai = *(const float4*)&A_s[wv][ii*4];
      float u =
          Ai.x * Qs[wv][(1+dd)*20 +  0 + jj] + Ai.y * Qs[wv][(1+dd)*20 +  4 + jj]
        + Ai.z * Qs[wv][(1+dd)*20 +  8 + jj] + Ai.w * Qs[wv][(1+dd)*20 + 12 + jj];
      float Adv = -( __shfl(u, 0, 4) * A_s[wv][ 0 + jj]
                   + __shfl(u, 1, 4) * A_s[wv][ 4 + jj]
                   + __shfl(u, 2, 4) * A_s[wv][ 8 + jj]
                   + __shfl(u, 3, 4) * A_s[wv][12 + jj] );
      Ad_s[wv][dd*16 + ii*4 + jj] = Adv;
    }
    wfence();

    // (e) R[(m,n)][i][j], 6 antisym pairs   [dde[p][q][r] = dde2[(p*4+q)*20+r]]
    {
      auto riem = [&](int m, int n) -> float {
        float4 Adm = *(const float4*)&Ad_s[wv][m*16 + ii*4];
        float4 Adn = *(const float4*)&Ad_s[wv][n*16 + ii*4];
        float4 Aiv = *(const float4*)&A_s[wv][ii*4];
        float a;
        a  = Adm.x * F_s[wv][n*16 +  0 + jj] - Adn.x * F_s[wv][m*16 +  0 + jj]
           + Aiv.x * (dde2[wv][(n*4+0)*20 + m*4 + jj] - dde2[wv][(m*4+0)*20 + n*4 + jj]);
        a += Adm.y * F_s[wv][n*16 +  4 + jj] - Adn.y * F_s[wv][m*16 +  4 + jj]
           + Aiv.y * (dde2[wv][(n*4+1)*20 + m*4 + jj] - dde2[wv][(m*4+1)*20 + n*4 + jj]);
        a += Adm.z * F_s[wv][n*16 +  8 + jj] - Adn.z * F_s[wv][m*16 +  8 + jj]
           + Aiv.z * (dde2[wv][(n*4+2)*20 + m*4 + jj] - dde2[wv][(m*4+2)*20 + n*4 + jj]);
        a += Adm.w * F_s[wv][n*16 + 12 + jj] - Adn.w * F_s[wv][m*16 + 12 + jj]
           + Aiv.w * (dde2[wv][(n*4+3)*20 + m*4 + jj] - dde2[wv][(m*4+3)*20 + n*4 + jj]);
        return 0.5f * eta_ii * a;
      };
      int m1 = (dd < 3) ? 0 : 1;
      int n1 = (dd < 3) ? (dd + 1) : 2;          // pairs 0..3: (0,1),(0,2),(0,3),(1,2)
      R_s[wv][dd*16 + ii*4 + jj] = riem(m1, n1);
      if (dd < 2)                                 // pairs 4,5: (1,3),(2,3)
        R_s[wv][(4 + dd)*16 + ii*4 + jj] = riem(dd + 1, 3);
    }
    wfence();

    // (f) riemann_out[k,l,i,j] = eta_k eta_l sum_p minor_p(A;k,l) R_p[i,j]
    {
      const int kl = lane >> 2, kk = kl >> 2, ll = kl & 3, i2 = lane & 3;
      float4 akv = *(const float4*)&A_s[wv][kk*4];
      float4 alv = *(const float4*)&A_s[wv][ll*4];
      float sgn = ((kk == 0) != (ll == 0)) ? -1.f : 1.f;
      float B0 = (akv.x*alv.y - akv.y*alv.x) * sgn;
      float B1 = (akv.x*alv.z - akv.z*alv.x) * sgn;
      float B2 = (akv.x*alv.w - akv.w*alv.x) * sgn;
      float B3 = (akv.y*alv.z - akv.z*alv.y) * sgn;
      float B4 = (akv.y*alv.w - akv.w*alv.y) * sgn;
      float B5 = (akv.z*alv.w - akv.w*alv.z) * sgn;
      float4 r0 = *(const float4*)&R_s[wv][ 0 + i2*4];
      float4 r1 = *(const float4*)&R_s[wv][16 + i2*4];
      float4 r2 = *(const float4*)&R_s[wv][32 + i2*4];
      float4 r3 = *(const float4*)&R_s[wv][48 + i2*4];
      float4 r4 = *(const float4*)&R_s[wv][64 + i2*4];
      float4 r5 = *(const float4*)&R_s[wv][80 + i2*4];
      float4 o;
      o.x = B0*r0.x + B1*r1.x + B2*r2.x + B3*r3.x + B4*r4.x + B5*r5.x;
      o.y = B0*r0.y + B1*r1.y + B2*r2.y + B3*r3.y + B4*r4.y + B5*r5.y;
      o.z = B0*r0.z + B1*r1.z + B2*r2.z + B3*r3.z + B4*r4.z + B5*r5.z;
      o.w = B0*r0.w + B1*r1.w + B2*r2.w + B3*r3.w + B4*r4.w + B5*r5.w;
      ((float4*)(out1 + ((size_t)s << 8)))[kl*4 + i2] = o;
    }
    // (g1) rp[m,j'] = sum over n of sgn * R[(m,n)] col-contraction with A
    if (ii == 0) {
      const int m = dd, ip = jj;
      float a = 0.f;
      #pragma unroll
      for (int n = 0; n < 4; ++n) {
        if (n != m) {
          int mm = (m < n) ? m : n;
          int nn = (m < n) ? n : m;
          int pr = mm * (7 - mm) / 2 + (nn - mm - 1);
          float sg = (m < n) ? 1.f : -1.f;
          float4 rr = *(const float4*)&R_s[wv][pr*16 + ip*4];
          a += sg * (rr.x * A_s[wv][0 + n] + rr.y * A_s[wv][4 + n]
                   + rr.z * A_s[wv][8 + n] + rr.w * A_s[wv][12 + n]);
        }
      }
      rp_s[wv][m*4 + ip] = a;
    }
    wfence();
    // (g2) ricci[i,j] = eta_i sum_m A[i,m] rp[m,j]
    if (dd == 0) {
      float4 Ai = *(const float4*)&A_s[wv][ii*4];
      float a = Ai.x * rp_s[wv][0 + jj] + Ai.y * rp_s[wv][4 + jj]
              + Ai.z * rp_s[wv][8 + jj] + Ai.w * rp_s[wv][12 + jj];
      out0[(size_t)s * 16 + ii*4 + jj] = eta_ii * a;
    }
  }
}

extern "C" void kernel_launch(void* const* d_in, const int* in_sizes, int n_in,
                              void* d_out, int out_size, void* d_ws, size_t ws_size,
                              hipStream_t stream) {
  (void)n_in; (void)out_size; (void)d_ws; (void)ws_size;
  const float* x  = (const float*)d_in[0];
  const float* W1 = (const float*)d_in[1];
  const float* b1 = (const float*)d_in[2];
  const float* W2 = (const float*)d_in[3];
  const float* b2 = (const float*)d_in[4];
  float* out = (float*)d_out;
  const int B = in_sizes[0] / 4;                 // 65536
  const int nblk = B / (WAVES * ITERS);          // 4096 blocks x 256 threads
  hipLaunchKernelGGL(ein_kernel, dim3(nblk), dim3(256), 0, stream,
                     x, W1, b1, W2, b2, out, B);
}

// Round 12
// 188.197 us; speedup vs baseline: 1.8010x; 1.3748x over previous
//
#include <hip/hip_runtime.h>
#include <cstdint>
#include <cstddef>

// EinsteinPINN — analytic forward-mode rewrite, MFMA pass-2, barrier-free waves.
// Round 11: spill root-cause found. Measured arch-VGPR caps: (256,2)->88ok,
// (256,3)->84ok, (256,4)->64 SPILL, (256,5)->48 SPILL => cap ~= 256/w (unified
// VGPR/AGPR split for MFMA kernels), NOT 512/w. Fix: launch_bounds(256,2) =
// allocator budget 128, natural ~88, no spill; RUNTIME occupancy is set by
// actual usage: 88 VGPR -> 16 waves/CU (m69 step at 128), LDS 31744*4=124KB
// -> 4 blocks/CU. Same occupancy (256,4) promised, without the spill.
// Math (verified rounds 1-10): e = I + 0.1*(W2 h + b2); de[m]=0.1*W2(g.*W1[:,m]);
//   dde[p,q]=0.1*W2(u.*W1[:,p].*W1[:,q]); h=tanh(z), g=1-h^2, u=-2hg.
//   A=inv(e); F = de - de^T(first two); Ad_d = -A de_d A;
//   riemann[m,n,i,j] = (eta_i/2) sum_a [Ad_m[i,a]F[n,a,j] - Ad_n[i,a]F[m,a,j]
//                                       + A[i,a](dde[n,a,m,j]-dde[m,a,n,j])]
//   (antisym in (m,n): 6 pairs). Outputs are cheap A-contractions of R.

typedef _Float16 h2   __attribute__((ext_vector_type(2)));
typedef _Float16 f16x8 __attribute__((ext_vector_type(8)));
typedef float    f32x4 __attribute__((ext_vector_type(4)));

#define WAVES 4
#define ITERS 4

__device__ __forceinline__ void wfence() {
  // order all prior LDS ops before subsequent ones, wave-locally (no s_barrier)
  asm volatile("s_waitcnt lgkmcnt(0)" ::: "memory");
  __builtin_amdgcn_sched_barrier(0);
}

__device__ __forceinline__ unsigned pkrtz(float a, float b) {
#if __has_builtin(__builtin_amdgcn_cvt_pkrtz)
  return __builtin_bit_cast(unsigned, __builtin_amdgcn_cvt_pkrtz(a, b));
#else
  h2 v; v[0] = (_Float16)a; v[1] = (_Float16)b;
  return __builtin_bit_cast(unsigned, v);
#endif
}

__global__ __launch_bounds__(256, 2) void ein_kernel(
    const float* __restrict__ x, const float* __restrict__ W1,
    const float* __restrict__ b1, const float* __restrict__ W2,
    const float* __restrict__ b2, float* __restrict__ out, int B)
{
  // ---- per-wave LDS (31744 B total; 4 blocks/CU with ~88 VGPR) ----
  __shared__ __align__(16) _Float16 Gt[WAVES][16][136]; // half-K G^T: [c][n0..127]+8 pad
  __shared__ __align__(16) float Qs[WAVES][320];        // M cols, stride 20: c*20 + r
  __shared__ __align__(16) float dde2[WAVES][320];      // [p*4+q][r], stride 20, sym-dup
  __shared__ __align__(16) float A_s[WAVES][16];
  __shared__ float F_s[WAVES][64];
  __shared__ float Ad_s[WAVES][64];
  __shared__ __align__(16) float R_s[WAVES][96];        // 6 pairs x 16
  __shared__ float rp_s[WAVES][16];

  const int tid  = threadIdx.x;
  const int wv   = tid >> 6;
  const int lane = tid & 63;
  const int l15  = lane & 15;
  const int hb   = lane >> 4;
  const int dd = lane >> 4, ii = (lane >> 2) & 3, jj = lane & 3;
  const float eta_ii = (ii == 0) ? -1.f : 1.f;

  // ---- loop-invariant register state ----
  // W1 rows + b1 for this lane's 4 neurons: 2*lane, 2*lane+1, 2*lane+128, 2*lane+129
  const float4 w1A = ((const float4*)W1)[2*lane];
  const float4 w1B = ((const float4*)W1)[2*lane + 1];
  const float4 w1C = ((const float4*)W1)[2*lane + 128];
  const float4 w1D = ((const float4*)W1)[2*lane + 129];
  const float b1A = b1[2*lane],       b1B = b1[2*lane + 1];
  const float b1C = b1[2*lane + 128], b1D = b1[2*lane + 129];
  // MFMA A-fragments: lane holds W2[row=l15][k = cc*32 + hb*8 + j], j=0..7
  f16x8 afr[8];
  #pragma unroll
  for (int cc = 0; cc < 8; ++cc) {
    const float* p = W2 + l15*256 + cc*32 + hb*8;
    float4 u0 = ((const float4*)p)[0];
    float4 u1 = ((const float4*)p)[1];
    f16x8 a;
    a[0]=(_Float16)u0.x; a[1]=(_Float16)u0.y; a[2]=(_Float16)u0.z; a[3]=(_Float16)u0.w;
    a[4]=(_Float16)u1.x; a[5]=(_Float16)u1.y; a[6]=(_Float16)u1.z; a[7]=(_Float16)u1.w;
    afr[cc] = a;
  }
  const float eb0 = b2[4*hb+0], eb1 = b2[4*hb+1], eb2 = b2[4*hb+2], eb3 = b2[4*hb+3];

  float* out0 = out;
  float* out1 = out + (size_t)B * 16;

  // per-neuron activation pieces: h, g*w (4), u*w (4)
  auto neuron = [](const float4& w, float b, const float4& xs,
                   float& h, float4& gw4, float4& uw4) {
    float z = b + w.x*xs.x + w.y*xs.y + w.z*xs.z + w.w*xs.w;
    float t  = __expf(-2.f * fabsf(z));
    float r1 = __builtin_amdgcn_rcpf(1.f + t);
    float habs = (1.f - t) * r1;
    h = (z < 0.f) ? -habs : habs;
    float g = 4.f * t * r1 * r1;         // sech^2, no cancellation
    float u = -2.f * h * g;
    gw4 = make_float4(g*w.x, g*w.y, g*w.z, g*w.w);
    uw4 = make_float4(u*w.x, u*w.y, u*w.z, u*w.w);
  };

  const int sbase = blockIdx.x * (WAVES * ITERS);
  float4 xs = ((const float4*)x)[sbase + wv];

  for (int it = 0; it < ITERS; ++it) {
    const int s = sbase + it * WAVES + wv;
    const float4 xc = xs;
    if (it + 1 < ITERS) xs = ((const float4*)x)[sbase + (it + 1) * WAVES + wv];

    // ---------- pass 1+2 interleaved: two half-K phases over one Gt buffer ----
    // stage: lane stages neuron pair (f16 packed); writes u32 word c*68 + lane
    unsigned* gwp = (unsigned*)&Gt[wv][0][0] + lane;   // row stride 68 u32
    auto stage_pair = [&](const float4& wA, float bA_, const float4& wB, float bB_) {
      float hA, hB; float4 gA, gB, uA, uB;
      neuron(wA, bA_, xc, hA, gA, uA);
      neuron(wB, bB_, xc, hB, gB, uB);
      gwp[0*68] = pkrtz(hA, hB);
      gwp[1*68] = pkrtz(gA.x, gB.x);  gwp[2*68] = pkrtz(gA.y, gB.y);
      gwp[3*68] = pkrtz(gA.z, gB.z);  gwp[4*68] = pkrtz(gA.w, gB.w);
      gwp[5*68]  = pkrtz(uA.x*wA.x, uB.x*wB.x);
      gwp[6*68]  = pkrtz(uA.x*wA.y, uB.x*wB.y);
      gwp[7*68]  = pkrtz(uA.x*wA.z, uB.x*wB.z);
      gwp[8*68]  = pkrtz(uA.x*wA.w, uB.x*wB.w);
      gwp[9*68]  = pkrtz(uA.y*wA.y, uB.y*wB.y);
      gwp[10*68] = pkrtz(uA.y*wA.z, uB.y*wB.z);
      gwp[11*68] = pkrtz(uA.y*wA.w, uB.y*wB.w);
      gwp[12*68] = pkrtz(uA.z*wA.z, uB.z*wB.z);
      gwp[13*68] = pkrtz(uA.z*wA.w, uB.z*wB.w);
      gwp[14*68] = pkrtz(uA.w*wA.w, uB.w*wB.w);
    };
    // B-frag reads: lane (l15,hb) reads Gt[l15][kk*32 + hb*8 ..+7] (16B aligned)
    const f16x8* gp = (const f16x8*)&Gt[wv][l15][hb*8];

    f32x4 acc = {0.f, 0.f, 0.f, 0.f};
    stage_pair(w1A, b1A, w1B, b1B);          // neurons 0..127
    wfence();
    #pragma unroll
    for (int kk = 0; kk < 4; ++kk) {
      f16x8 bfr = gp[kk * 4];
      acc = __builtin_amdgcn_mfma_f32_16x16x32_f16(afr[kk], bfr, acc, 0, 0, 0);
    }
    wfence();                                 // reads drained before overwrite
    stage_pair(w1C, b1C, w1D, b1D);          // neurons 128..255
    wfence();
    #pragma unroll
    for (int kk = 0; kk < 4; ++kk) {
      f16x8 bfr = gp[kk * 4];
      acc = __builtin_amdgcn_mfma_f32_16x16x32_f16(afr[4 + kk], bfr, acc, 0, 0, 0);
    }

    // ---------- writeback: lane holds M[r=4*hb+q][c=l15] in acc[q] ----------
    {
      float v0 = 0.1f*acc[0], v1 = 0.1f*acc[1], v2 = 0.1f*acc[2], v3 = 0.1f*acc[3];
      if (l15 == 0) {   // e column: + 0.1*b2 + I   (r=4hb+q -> i=hb, j=q)
        v0 += 0.1f*eb0 + ((hb == 0) ? 1.f : 0.f);
        v1 += 0.1f*eb1 + ((hb == 1) ? 1.f : 0.f);
        v2 += 0.1f*eb2 + ((hb == 2) ? 1.f : 0.f);
        v3 += 0.1f*eb3 + ((hb == 3) ? 1.f : 0.f);
      }
      float4 v4 = make_float4(v0, v1, v2, v3);
      *(float4*)&Qs[wv][l15*20 + hb*4] = v4;
      if (l15 >= 5 && l15 <= 14) {       // dde columns -> [p][q] grid with sym dup
        int t = l15 - 5;                  // 0..9, pairs (0,0),(0,1),(0,2),(0,3),(1,1),...
        int p = (t >= 9) ? 3 : (t >= 7) ? 2 : (t >= 4) ? 1 : 0;
        int q = t - ((p * (7 - p)) >> 1);
        *(float4*)&dde2[wv][(p*4 + q)*20 + hb*4] = v4;
        if (p != q) *(float4*)&dde2[wv][(q*4 + p)*20 + hb*4] = v4;
      }
    }
    wfence();

    // ---------- phase 3 ----------
    // (a) A = inv(e), all lanes redundant (cofactor)
    {
      float4 er0 = *(const float4*)&Qs[wv][0];
      float4 er1 = *(const float4*)&Qs[wv][4];
      float4 er2 = *(const float4*)&Qs[wv][8];
      float4 er3 = *(const float4*)&Qs[wv][12];
      float m00=er0.x,m01=er0.y,m02=er0.z,m03=er0.w;
      float m10=er1.x,m11=er1.y,m12=er1.z,m13=er1.w;
      float m20=er2.x,m21=er2.y,m22=er2.z,m23=er2.w;
      float m30=er3.x,m31=er3.y,m32=er3.z,m33=er3.w;
      float s0_=m00*m11-m01*m10, s1_=m00*m12-m02*m10, s2_=m00*m13-m03*m10;
      float s3_=m01*m12-m02*m11, s4_=m01*m13-m03*m11, s5_=m02*m13-m03*m12;
      float c5_=m22*m33-m23*m32, c4_=m21*m33-m23*m31, c3_=m21*m32-m22*m31;
      float c2_=m20*m33-m23*m30, c1_=m20*m32-m22*m30, c0_=m20*m31-m21*m30;
      float det = s0_*c5_ - s1_*c4_ + s2_*c3_ + s3_*c2_ - s4_*c1_ + s5_*c0_;
      float inv = 1.0f / det;
      if (lane == 0) {
        *(float4*)&A_s[wv][0]  = make_float4(( m11*c5_-m12*c4_+m13*c3_)*inv,
                                             (-m01*c5_+m02*c4_-m03*c3_)*inv,
                                             ( m31*s5_-m32*s4_+m33*s3_)*inv,
                                             (-m21*s5_+m22*s4_-m23*s3_)*inv);
        *(float4*)&A_s[wv][4]  = make_float4((-m10*c5_+m12*c2_-m13*c1_)*inv,
                                             ( m00*c5_-m02*c2_+m03*c1_)*inv,
                                             (-m30*s5_+m32*s2_-m33*s1_)*inv,
                                             ( m20*s5_-m22*s2_+m23*s1_)*inv);
        *(float4*)&A_s[wv][8]  = make_float4(( m10*c4_-m11*c2_+m13*c0_)*inv,
                                             (-m00*c4_+m01*c2_-m03*c0_)*inv,
                                             ( m30*s4_-m31*s2_+m33*s0_)*inv,
                                             (-m20*s4_+m21*s2_-m23*s0_)*inv);
        *(float4*)&A_s[wv][12] = make_float4((-m10*c3_+m11*c1_-m12*c0_)*inv,
                                             ( m00*c3_-m01*c1_+m02*c0_)*inv,
                                             (-m30*s3_+m31*s1_-m32*s0_)*inv,
                                             ( m20*s3_-m21*s1_+m22*s0_)*inv);
      }
    }
    wfence();

    // (b) F = de - de^T(first two); (c) u = A[ii,:].de[dd,:,jj];
    // (d) Ad_d = -U_d A via quad-shuffle (U row lives in this 4-lane group)
    F_s[wv][dd*16 + ii*4 + jj] = Qs[wv][(1+dd)*20 + ii*4 + jj]
                               - Qs[wv][(1+ii)*20 + dd*4 + jj];
    {
      float4 Ai = *(const float4*)&A_s[wv][ii*4];
      float u =
          Ai.x * Qs[wv][(1+dd)*20 +  0 + jj] + Ai.y * Qs[wv][(1+dd)*20 +  4 + jj]
        + Ai.z * Qs[wv][(1+dd)*20 +  8 + jj] + Ai.w * Qs[wv][(1+dd)*20 + 12 + jj];
      float Adv = -( __shfl(u, 0, 4) * A_s[wv][ 0 + jj]
                   + __shfl(u, 1, 4) * A_s[wv][ 4 + jj]
                   + __shfl(u, 2, 4) * A_s[wv][ 8 + jj]
                   + __shfl(u, 3, 4) * A_s[wv][12 + jj] );
      Ad_s[wv][dd*16 + ii*4 + jj] = Adv;
    }
    wfence();

    // (e) R[(m,n)][i][j], 6 antisym pairs   [dde[p][q][r] = dde2[(p*4+q)*20+r]]
    {
      auto riem = [&](int m, int n) -> float {
        float4 Adm = *(const float4*)&Ad_s[wv][m*16 + ii*4];
        float4 Adn = *(const float4*)&Ad_s[wv][n*16 + ii*4];
        float4 Aiv = *(const float4*)&A_s[wv][ii*4];
        float a;
        a  = Adm.x * F_s[wv][n*16 +  0 + jj] - Adn.x * F_s[wv][m*16 +  0 + jj]
           + Aiv.x * (dde2[wv][(n*4+0)*20 + m*4 + jj] - dde2[wv][(m*4+0)*20 + n*4 + jj]);
        a += Adm.y * F_s[wv][n*16 +  4 + jj] - Adn.y * F_s[wv][m*16 +  4 + jj]
           + Aiv.y * (dde2[wv][(n*4+1)*20 + m*4 + jj] - dde2[wv][(m*4+1)*20 + n*4 + jj]);
        a += Adm.z * F_s[wv][n*16 +  8 + jj] - Adn.z * F_s[wv][m*16 +  8 + jj]
           + Aiv.z * (dde2[wv][(n*4+2)*20 + m*4 + jj] - dde2[wv][(m*4+2)*20 + n*4 + jj]);
        a += Adm.w * F_s[wv][n*16 + 12 + jj] - Adn.w * F_s[wv][m*16 + 12 + jj]
           + Aiv.w * (dde2[wv][(n*4+3)*20 + m*4 + jj] - dde2[wv][(m*4+3)*20 + n*4 + jj]);
        return 0.5f * eta_ii * a;
      };
      int m1 = (dd < 3) ? 0 : 1;
      int n1 = (dd < 3) ? (dd + 1) : 2;          // pairs 0..3: (0,1),(0,2),(0,3),(1,2)
      R_s[wv][dd*16 + ii*4 + jj] = riem(m1, n1);
      if (dd < 2)                                 // pairs 4,5: (1,3),(2,3)
        R_s[wv][(4 + dd)*16 + ii*4 + jj] = riem(dd + 1, 3);
    }
    wfence();

    // (f) riemann_out[k,l,i,j] = eta_k eta_l sum_p minor_p(A;k,l) R_p[i,j]
    {
      const int kl = lane >> 2, kk = kl >> 2, ll = kl & 3, i2 = lane & 3;
      float4 akv = *(const float4*)&A_s[wv][kk*4];
      float4 alv = *(const float4*)&A_s[wv][ll*4];
      float sgn = ((kk == 0) != (ll == 0)) ? -1.f : 1.f;
      float B0 = (akv.x*alv.y - akv.y*alv.x) * sgn;
      float B1 = (akv.x*alv.z - akv.z*alv.x) * sgn;
      float B2 = (akv.x*alv.w - akv.w*alv.x) * sgn;
      float B3 = (akv.y*alv.z - akv.z*alv.y) * sgn;
      float B4 = (akv.y*alv.w - akv.w*alv.y) * sgn;
      float B5 = (akv.z*alv.w - akv.w*alv.z) * sgn;
      float4 r0 = *(const float4*)&R_s[wv][ 0 + i2*4];
      float4 r1 = *(const float4*)&R_s[wv][16 + i2*4];
      float4 r2 = *(const float4*)&R_s[wv][32 + i2*4];
      float4 r3 = *(const float4*)&R_s[wv][48 + i2*4];
      float4 r4 = *(const float4*)&R_s[wv][64 + i2*4];
      float4 r5 = *(const float4*)&R_s[wv][80 + i2*4];
      float4 o;
      o.x = B0*r0.x + B1*r1.x + B2*r2.x + B3*r3.x + B4*r4.x + B5*r5.x;
      o.y = B0*r0.y + B1*r1.y + B2*r2.y + B3*r3.y + B4*r4.y + B5*r5.y;
      o.z = B0*r0.z + B1*r1.z + B2*r2.z + B3*r3.z + B4*r4.z + B5*r5.z;
      o.w = B0*r0.w + B1*r1.w + B2*r2.w + B3*r3.w + B4*r4.w + B5*r5.w;
      ((float4*)(out1 + ((size_t)s << 8)))[kl*4 + i2] = o;
    }
    // (g1) rp[m,j'] = sum over n of sgn * R[(m,n)] col-contraction with A
    if (ii == 0) {
      const int m = dd, ip = jj;
      float a = 0.f;
      #pragma unroll
      for (int n = 0; n < 4; ++n) {
        if (n != m) {
          int mm = (m < n) ? m : n;
          int nn = (m < n) ? n : m;
          int pr = mm * (7 - mm) / 2 + (nn - mm - 1);
          float sg = (m < n) ? 1.f : -1.f;
          float4 rr = *(const float4*)&R_s[wv][pr*16 + ip*4];
          a += sg * (rr.x * A_s[wv][0 + n] + rr.y * A_s[wv][4 + n]
                   + rr.z * A_s[wv][8 + n] + rr.w * A_s[wv][12 + n]);
        }
      }
      rp_s[wv][m*4 + ip] = a;
    }
    wfence();
    // (g2) ricci[i,j] = eta_i sum_m A[i,m] rp[m,j]
    if (dd == 0) {
      float4 Ai = *(const float4*)&A_s[wv][ii*4];
      float a = Ai.x * rp_s[wv][0 + jj] + Ai.y * rp_s[wv][4 + jj]
              + Ai.z * rp_s[wv][8 + jj] + Ai.w * rp_s[wv][12 + jj];
      out0[(size_t)s * 16 + ii*4 + jj] = eta_ii * a;
    }
  }
}

extern "C" void kernel_launch(void* const* d_in, const int* in_sizes, int n_in,
                              void* d_out, int out_size, void* d_ws, size_t ws_size,
                              hipStream_t stream) {
  (void)n_in; (void)out_size; (void)d_ws; (void)ws_size;
  const float* x  = (const float*)d_in[0];
  const float* W1 = (const float*)d_in[1];
  const float* b1 = (const float*)d_in[2];
  const float* W2 = (const float*)d_in[3];
  const float* b2 = (const float*)d_in[4];
  float* out = (float*)d_out;
  const int B = in_sizes[0] / 4;                 // 65536
  const int nblk = B / (WAVES * ITERS);          // 4096 blocks x 256 threads
  hipLaunchKernelGGL(ein_kernel, dim3(nblk), dim3(256), 0, stream,
                     x, W1, b1, W2, b2, out, B);
}